// Round 1
// baseline (535.898 us; speedup 1.0000x reference)
//
#include <hip/hip_runtime.h>
#include <hip/hip_bf16.h>

#define B 16
#define L 64
#define P 1024
#define V 64
#define Q 16
#define LN64 4.158883083359672f

__device__ __forceinline__ float bf2f(ushort u) {
    return __uint_as_float(((unsigned int)u) << 16);
}
__device__ __forceinline__ ushort f2bf(float f) {
    unsigned int x = __float_as_uint(f);
    unsigned int r = (x + 0x7fffu + ((x >> 16) & 1u)) >> 16;
    return (ushort)r;
}

__device__ __forceinline__ float wsum64(float v) {
#pragma unroll
    for (int m = 32; m > 0; m >>= 1) v += __shfl_xor(v, m, 64);
    return v;
}
__device__ __forceinline__ float wmax64(float v) {
#pragma unroll
    for (int m = 32; m > 0; m >>= 1) v = fmaxf(v, __shfl_xor(v, m, 64));
    return v;
}

// ---------------------------------------------------------------------------
// K_uhat: one wave per (l,p) tile. Computes u[b,v] = sum_q W[l,p,v,q]*x[b,p,q]
// for the whole 16x64 tile via 4x4 register blocking per lane.
// lane = (b4<<4) | v4 ; lane owns b in [4*b4,4*b4+4), v in [4*v4,4*v4+4).
// Writes bf16 u_hat[b][l][p][v].
// ---------------------------------------------------------------------------
__global__ __launch_bounds__(256) void k_uhat(const float* __restrict__ Wt,
                                              const float* __restrict__ x,
                                              ushort* __restrict__ uhat) {
    const int wave = threadIdx.x >> 6;
    const int lane = threadIdx.x & 63;
    const int tile = blockIdx.x * 4 + wave;   // 0..65535 = l*1024 + p
    const int l = tile >> 10;
    const int p = tile & 1023;
    const int b4 = lane >> 4;   // 0..3
    const int v4 = lane & 15;   // 0..15

    const float4* Wp = reinterpret_cast<const float4*>(Wt + (size_t)(l * P + p) * (V * Q));

    float4 Xr[4][4];   // [i][q4] : b = 4*b4+i
    float4 Wr[4][4];   // [j][q4] : v = 4*v4+j
#pragma unroll
    for (int i = 0; i < 4; ++i) {
        const int b = b4 * 4 + i;
        const float4* xb = reinterpret_cast<const float4*>(x + ((size_t)b * P + p) * Q);
#pragma unroll
        for (int q4 = 0; q4 < 4; ++q4) Xr[i][q4] = xb[q4];
    }
#pragma unroll
    for (int j = 0; j < 4; ++j) {
        const int v = v4 * 4 + j;
#pragma unroll
        for (int q4 = 0; q4 < 4; ++q4) Wr[j][q4] = Wp[v * 4 + q4];
    }

#pragma unroll
    for (int i = 0; i < 4; ++i) {
        const int b = b4 * 4 + i;
        float uu[4];
#pragma unroll
        for (int j = 0; j < 4; ++j) {
            float u = 0.f;
#pragma unroll
            for (int q4 = 0; q4 < 4; ++q4) {
                float4 a = Xr[i][q4], w = Wr[j][q4];
                u = fmaf(a.x, w.x, u);
                u = fmaf(a.y, w.y, u);
                u = fmaf(a.z, w.z, u);
                u = fmaf(a.w, w.w, u);
            }
            uu[j] = u;
        }
        ushort4 pk;
        pk.x = f2bf(uu[0]); pk.y = f2bf(uu[1]); pk.z = f2bf(uu[2]); pk.w = f2bf(uu[3]);
        size_t idx = (((size_t)(b * L + l)) * P + p) * V + v4 * 4;
        *reinterpret_cast<ushort4*>(uhat + idx) = pk;
    }
}

// ---------------------------------------------------------------------------
// K_s: per (b,l) block (grid 64x16), 256 threads (4 waves).
// s[v] = sum_p c[b,l,p] * u_hat[b,l,p,v]; fused squash -> vout[b,l,v].
// c == nullptr -> uniform 1/64 (iteration 0).
// norms != nullptr -> also write |squash(s)| per (b,l) (final iteration).
// ---------------------------------------------------------------------------
__global__ __launch_bounds__(256) void k_s(const ushort* __restrict__ uhat,
                                           const float* __restrict__ c,
                                           float* __restrict__ vout,
                                           float* __restrict__ norms) {
    const int l = blockIdx.x, b = blockIdx.y;
    const int w = threadIdx.x >> 6, v = threadIdx.x & 63;
    const ushort* up = uhat + ((size_t)(b * L + l)) * P * V;
    float acc = 0.f;
    if (c) {
        const float* cp = c + (size_t)(b * L + l) * P;
#pragma unroll 8
        for (int p = w; p < P; p += 4)
            acc = fmaf(cp[p], bf2f(up[(size_t)p * V + v]), acc);
    } else {
#pragma unroll 8
        for (int p = w; p < P; p += 4)
            acc += bf2f(up[(size_t)p * V + v]);
        acc *= (1.0f / 64.0f);
    }
    __shared__ float sl[4][64];
    sl[w][v] = acc;
    __syncthreads();
    if (w == 0) {
        float s = sl[0][v] + sl[1][v] + sl[2][v] + sl[3][v];
        float sq = wsum64(s * s);
        float f = sqrtf(sq) / (1.0f + sq);
        vout[(size_t)(b * L + l) * V + v] = s * f;
        if (norms && v == 0) norms[b * L + l] = sq / (1.0f + sq);
    }
}

// ---------------------------------------------------------------------------
// K_bc: per (b,p) block (grid 1024x16), 256 threads (4 waves, 16 l each).
// db[l] = sum_v vv[b,l,v]*u_hat[b,l,p,v]; b_new = (add_prev? b_old:0) + db;
// c[b,l,p] = softmax_l(b_new); optional entropy partial for T.
// ---------------------------------------------------------------------------
__global__ __launch_bounds__(256) void k_bc(const ushort* __restrict__ uhat,
                                            const float* __restrict__ vv,
                                            float* __restrict__ bbuf,
                                            float* __restrict__ cbuf,
                                            float* __restrict__ Tsum,
                                            int add_prev, int do_T) {
    const int p = blockIdx.x, b = blockIdx.y;
    const int w = threadIdx.x >> 6, lane = threadIdx.x & 63;
    __shared__ float bl[64];
#pragma unroll 4
    for (int li = 0; li < 16; ++li) {
        const int l = w * 16 + li;
        float u = bf2f(uhat[(((size_t)(b * L + l)) * P + p) * V + lane]);
        float t = u * vv[(size_t)(b * L + l) * V + lane];
        t = wsum64(t);
        if (lane == 0) bl[l] = t;
    }
    __syncthreads();
    if (w == 0) {
        float bv = bl[lane];
        float* bp = bbuf + ((size_t)b * P + p) * L;
        if (add_prev) bv += bp[lane];
        bp[lane] = bv;
        float m = wmax64(bv);
        float e = expf(bv - m);
        float ssum = wsum64(e);
        float cc = e / ssum;
        cbuf[((size_t)b * L + lane) * P + p] = cc;
        if (do_T) {
            // 1 - H/ln64 == sum_l c*ln(64*(c+eps)) / ln64  (cancellation-free)
            float term = cc * logf(64.0f * (cc + 1e-12f));
            float dsum = wsum64(term);
            if (lane == 0) atomicAdd(Tsum, dsum * (1.0f / LN64));
        }
    }
}

// ---------------------------------------------------------------------------
// K_final: T and D. One block, 64 threads (lane = l).
// ---------------------------------------------------------------------------
__global__ void k_final(const float* __restrict__ Tsum,
                        const float* __restrict__ norms,
                        float* __restrict__ out) {
    const int lane = threadIdx.x & 63;
    float n[B];
    float sum = 0.f;
#pragma unroll
    for (int b = 0; b < B; ++b) { n[b] = norms[b * L + lane]; sum += n[b]; }
    const float mean = sum * (1.0f / B);
    float var = 0.f;
#pragma unroll
    for (int b = 0; b < B; ++b) { float d = n[b] - mean; var = fmaf(d, d, var); }
    var *= (1.0f / B);
    float sd = sqrtf(var);
    float D = wmax64(sd);
    if (lane == 0) {
        out[B * L * V] = Tsum[0] * (1.0f / (B * P));
        out[B * L * V + 1] = D;
    }
}

extern "C" void kernel_launch(void* const* d_in, const int* in_sizes, int n_in,
                              void* d_out, int out_size, void* d_ws, size_t ws_size,
                              hipStream_t stream) {
    const float* x = (const float*)d_in[0];   // (B,P,Q)
    const float* W = (const float*)d_in[1];   // (L,P,V,Q)
    float* out = (float*)d_out;               // v (B,L,V) then T, D

    char* ws = (char*)d_ws;
    ushort* uhat = (ushort*)ws;                       // B*L*P*V bf16 = 134,217,728 B
    size_t off = (size_t)B * L * P * V * 2;
    float* vbuf = (float*)(ws + off);  off += (size_t)B * L * V * 4;   // 256 KB
    float* bbuf = (float*)(ws + off);  off += (size_t)B * P * L * 4;   // 4 MB (layout B,P,L)
    float* cbuf = (float*)(ws + off);  off += (size_t)B * L * P * 4;   // 4 MB (layout B,L,P)
    float* norms = (float*)(ws + off); off += (size_t)B * L * 4;
    float* Tsum = (float*)(ws + off);  off += 256;

    hipMemsetAsync(Tsum, 0, sizeof(float), stream);

    // u_hat (bf16)
    hipLaunchKernelGGL(k_uhat, dim3(16384), dim3(256), 0, stream, W, x, uhat);
    // iter 0: c uniform -> s -> squash -> v0
    hipLaunchKernelGGL(k_s, dim3(L, B), dim3(256), 0, stream, uhat, (const float*)nullptr, vbuf, (float*)nullptr);
    // b1 = v0 . u_hat ; c1 = softmax_l(b1)
    hipLaunchKernelGGL(k_bc, dim3(P, B), dim3(256), 0, stream, uhat, vbuf, bbuf, cbuf, Tsum, 0, 0);
    // iter 1: s(c1) -> v1
    hipLaunchKernelGGL(k_s, dim3(L, B), dim3(256), 0, stream, uhat, cbuf, vbuf, (float*)nullptr);
    // b2 = b1 + v1 . u_hat ; c2 = softmax_l(b2); entropy partials for T
    hipLaunchKernelGGL(k_bc, dim3(P, B), dim3(256), 0, stream, uhat, vbuf, bbuf, cbuf, Tsum, 1, 1);
    // iter 2: s(c2) -> v2 -> d_out, norms
    hipLaunchKernelGGL(k_s, dim3(L, B), dim3(256), 0, stream, uhat, cbuf, out, norms);
    // T, D
    hipLaunchKernelGGL(k_final, dim3(1), dim3(64), 0, stream, Tsum, norms, out);
}

// Round 2
// 346.277 us; speedup vs baseline: 1.5476x; 1.5476x over previous
//
#include <hip/hip_runtime.h>
#include <hip/hip_bf16.h>

#define B 16
#define L 64
#define P 1024
#define V 64
#define Q 16
#define LN64 4.158883083359672f

static __device__ __forceinline__ float bf2f(ushort u) {
    return __uint_as_float(((unsigned int)u) << 16);
}
static __device__ __forceinline__ ushort f2bf(float f) {
    unsigned int x = __float_as_uint(f);
    unsigned int r = (x + 0x7fffu + ((x >> 16) & 1u)) >> 16;
    return (ushort)r;
}

static __device__ __forceinline__ float wsum64(float v) {
#pragma unroll
    for (int m = 32; m > 0; m >>= 1) v += __shfl_xor(v, m, 64);
    return v;
}
static __device__ __forceinline__ float wmax64(float v) {
#pragma unroll
    for (int m = 32; m > 0; m >>= 1) v = fmaxf(v, __shfl_xor(v, m, 64));
    return v;
}

// ---------------------------------------------------------------------------
// K_uhat: one wave per (l,p) tile. u[b,v] = sum_q W[l,p,v,q]*x[b,p,q] for the
// 16x64 (b,v) tile via 4x4 register blocking per lane. Writes bf16 uhat[b,l,p,v].
// ---------------------------------------------------------------------------
__global__ __launch_bounds__(256) void k_uhat(const float* __restrict__ Wt,
                                              const float* __restrict__ x,
                                              ushort* __restrict__ uhat) {
    const int wave = threadIdx.x >> 6;
    const int lane = threadIdx.x & 63;
    const int tile = blockIdx.x * 4 + wave;   // l*1024 + p
    const int l = tile >> 10;
    const int p = tile & 1023;
    const int b4 = lane >> 4;
    const int v4 = lane & 15;

    const float4* Wp = reinterpret_cast<const float4*>(Wt + (size_t)(l * P + p) * (V * Q));

    float4 Xr[4][4];
    float4 Wr[4][4];
#pragma unroll
    for (int i = 0; i < 4; ++i) {
        const int b = b4 * 4 + i;
        const float4* xb = reinterpret_cast<const float4*>(x + ((size_t)b * P + p) * Q);
#pragma unroll
        for (int q4 = 0; q4 < 4; ++q4) Xr[i][q4] = xb[q4];
    }
#pragma unroll
    for (int j = 0; j < 4; ++j) {
        const int v = v4 * 4 + j;
#pragma unroll
        for (int q4 = 0; q4 < 4; ++q4) Wr[j][q4] = Wp[v * 4 + q4];
    }

#pragma unroll
    for (int i = 0; i < 4; ++i) {
        const int b = b4 * 4 + i;
        float uu[4];
#pragma unroll
        for (int j = 0; j < 4; ++j) {
            float u = 0.f;
#pragma unroll
            for (int q4 = 0; q4 < 4; ++q4) {
                float4 a = Xr[i][q4], w = Wr[j][q4];
                u = fmaf(a.x, w.x, u);
                u = fmaf(a.y, w.y, u);
                u = fmaf(a.z, w.z, u);
                u = fmaf(a.w, w.w, u);
            }
            uu[j] = u;
        }
        ushort4 pk;
        pk.x = f2bf(uu[0]); pk.y = f2bf(uu[1]); pk.z = f2bf(uu[2]); pk.w = f2bf(uu[3]);
        size_t idx = (((size_t)(b * L + l)) * P + p) * V + v4 * 4;
        *reinterpret_cast<ushort4*>(uhat + idx) = pk;
    }
}

// ---------------------------------------------------------------------------
// K_s: per (b,l) block. s[v] = sum_p c[p]*u[p,v], fused squash.
// Thread t owns (pl = t>>4, v0 = (t&15)*4); ushort4 loads; c staged in LDS.
// ---------------------------------------------------------------------------
__global__ __launch_bounds__(256) void k_s(const ushort* __restrict__ uhat,
                                           const float* __restrict__ c,
                                           float* __restrict__ vout,
                                           float* __restrict__ norms) {
    const int l = blockIdx.x, b = blockIdx.y;
    const int t = threadIdx.x;
    const int w = t >> 6, lane = t & 63;
    const int pl = t >> 4;      // 0..15
    const int vg = t & 15;      // v0 = vg*4

    __shared__ float csh[P];        // 4 KB
    __shared__ float4 sl[4][16];    // 1 KB

    const ushort* up = uhat + ((size_t)(b * L + l)) * P * V + (size_t)pl * V + vg * 4;

    float4 acc = {0.f, 0.f, 0.f, 0.f};
    if (c) {
        const float* cp = c + (size_t)(b * L + l) * P;
        reinterpret_cast<float4*>(csh)[t] = reinterpret_cast<const float4*>(cp)[t];
        __syncthreads();
#pragma unroll 8
        for (int i = 0; i < 64; ++i) {
            ushort4 u = *reinterpret_cast<const ushort4*>(up + (size_t)i * 16 * V);
            float cc = csh[pl + i * 16];
            acc.x = fmaf(cc, bf2f(u.x), acc.x);
            acc.y = fmaf(cc, bf2f(u.y), acc.y);
            acc.z = fmaf(cc, bf2f(u.z), acc.z);
            acc.w = fmaf(cc, bf2f(u.w), acc.w);
        }
    } else {
#pragma unroll 8
        for (int i = 0; i < 64; ++i) {
            ushort4 u = *reinterpret_cast<const ushort4*>(up + (size_t)i * 16 * V);
            acc.x += bf2f(u.x); acc.y += bf2f(u.y);
            acc.z += bf2f(u.z); acc.w += bf2f(u.w);
        }
        acc.x *= (1.f / 64.f); acc.y *= (1.f / 64.f);
        acc.z *= (1.f / 64.f); acc.w *= (1.f / 64.f);
    }
    // reduce the 4 pl-groups within the wave (lane bits 4,5)
#pragma unroll
    for (int m = 16; m <= 32; m <<= 1) {
        acc.x += __shfl_xor(acc.x, m, 64);
        acc.y += __shfl_xor(acc.y, m, 64);
        acc.z += __shfl_xor(acc.z, m, 64);
        acc.w += __shfl_xor(acc.w, m, 64);
    }
    if (lane < 16) sl[w][vg] = acc;
    __syncthreads();
    if (w == 0 && lane < 16) {
        float4 s0 = sl[0][vg], s1 = sl[1][vg], s2 = sl[2][vg], s3 = sl[3][vg];
        float4 s;
        s.x = s0.x + s1.x + s2.x + s3.x;
        s.y = s0.y + s1.y + s2.y + s3.y;
        s.z = s0.z + s1.z + s2.z + s3.z;
        s.w = s0.w + s1.w + s2.w + s3.w;
        float sq = s.x * s.x + s.y * s.y + s.z * s.z + s.w * s.w;
        sq += __shfl_xor(sq, 1, 64);
        sq += __shfl_xor(sq, 2, 64);
        sq += __shfl_xor(sq, 4, 64);
        sq += __shfl_xor(sq, 8, 64);
        float f = sqrtf(sq) / (1.0f + sq);
        float4 o = {s.x * f, s.y * f, s.z * f, s.w * f};
        *reinterpret_cast<float4*>(vout + (size_t)(b * L + l) * V + vg * 4) = o;
        if (norms && lane == 0) norms[b * L + l] = sq / (1.0f + sq);
    }
}

// ---------------------------------------------------------------------------
// K_bc: block = (b, 16 consecutive p). Phase 1: db[l,p] = sum_v v[l,v]*u[l,p,v]
// streamed coalesced over l (thread owns (pl, v0), 16-lane reduce).
// Phase 2: each wave softmaxes 4 p's over l; coalesced transpose-write of c.
// bbuf layout (B,P,L); cbuf layout (B,L,P).
// ---------------------------------------------------------------------------
__global__ __launch_bounds__(256) void k_bc(const ushort* __restrict__ uhat,
                                            const float* __restrict__ vv,
                                            float* __restrict__ bbuf,
                                            float* __restrict__ cbuf,
                                            float* __restrict__ Tsum,
                                            int add_prev, int do_T) {
    const int p0 = blockIdx.x * 16, b = blockIdx.y;
    const int t = threadIdx.x;
    const int w = t >> 6, lane = t & 63;
    const int pl = t >> 4;      // 0..15
    const int vg = t & 15;      // v0 = vg*4

    __shared__ float vsh[L][V];        // 16 KB
    __shared__ float bl[16][L + 1];    // db[p][l]
    __shared__ float ct[16][L + 1];    // c[p][l]

    // stage v[b,:,:] in LDS
    {
        const float4* vvp = reinterpret_cast<const float4*>(vv + (size_t)b * L * V);
        float4* vshp = reinterpret_cast<float4*>(&vsh[0][0]);
#pragma unroll
        for (int i = 0; i < 4; ++i) vshp[t + i * 256] = vvp[t + i * 256];
    }
    __syncthreads();

    // phase 1: stream u_hat, 16-lane reduce over v
    const ushort* up = uhat + (((size_t)b * L) * P + p0 + pl) * V + vg * 4;
#pragma unroll 8
    for (int l = 0; l < L; ++l) {
        ushort4 u = *reinterpret_cast<const ushort4*>(up + (size_t)l * P * V);
        float4 vf = *reinterpret_cast<const float4*>(&vsh[l][vg * 4]);
        float tacc = bf2f(u.x) * vf.x + bf2f(u.y) * vf.y +
                     bf2f(u.z) * vf.z + bf2f(u.w) * vf.w;
        tacc += __shfl_xor(tacc, 1, 64);
        tacc += __shfl_xor(tacc, 2, 64);
        tacc += __shfl_xor(tacc, 4, 64);
        tacc += __shfl_xor(tacc, 8, 64);
        if (vg == 0) bl[pl][l] = tacc;
    }
    __syncthreads();

    // phase 2: each wave softmaxes 4 p's (lane = l)
    float tloc = 0.f;
#pragma unroll
    for (int pi = 0; pi < 4; ++pi) {
        const int pli = w * 4 + pi;
        const int p = p0 + pli;
        float bv = bl[pli][lane];
        float* bp = bbuf + ((size_t)b * P + p) * L;
        if (add_prev) bv += bp[lane];
        bp[lane] = bv;
        float m = wmax64(bv);
        float e = __expf(bv - m);
        float ssum = wsum64(e);
        float cc = e / ssum;
        ct[pli][lane] = cc;
        if (do_T) tloc += cc * __logf(64.0f * (cc + 1e-12f));
    }
    if (do_T) {
        float dsum = wsum64(tloc);
        if (lane == 0) atomicAdd(Tsum, dsum * (1.0f / LN64));
    }
    __syncthreads();

    // coalesced transpose-write of c: thread t -> (l = t>>2, p = (t&3)*4 ..+3)
    {
        const int l = t >> 2, pq = (t & 3) * 4;
        float4 cw;
        cw.x = ct[pq + 0][l];
        cw.y = ct[pq + 1][l];
        cw.z = ct[pq + 2][l];
        cw.w = ct[pq + 3][l];
        *reinterpret_cast<float4*>(cbuf + ((size_t)b * L + l) * P + p0 + pq) = cw;
    }
}

// ---------------------------------------------------------------------------
// K_final: T and D. One block, 64 threads (lane = l).
// ---------------------------------------------------------------------------
__global__ void k_final(const float* __restrict__ Tsum,
                        const float* __restrict__ norms,
                        float* __restrict__ out) {
    const int lane = threadIdx.x & 63;
    float n[B];
    float sum = 0.f;
#pragma unroll
    for (int b = 0; b < B; ++b) { n[b] = norms[b * L + lane]; sum += n[b]; }
    const float mean = sum * (1.0f / B);
    float var = 0.f;
#pragma unroll
    for (int b = 0; b < B; ++b) { float d = n[b] - mean; var = fmaf(d, d, var); }
    var *= (1.0f / B);
    float sd = sqrtf(var);
    float D = wmax64(sd);
    if (lane == 0) {
        out[B * L * V] = Tsum[0] * (1.0f / (B * P));
        out[B * L * V + 1] = D;
    }
}

extern "C" void kernel_launch(void* const* d_in, const int* in_sizes, int n_in,
                              void* d_out, int out_size, void* d_ws, size_t ws_size,
                              hipStream_t stream) {
    const float* x = (const float*)d_in[0];   // (B,P,Q)
    const float* W = (const float*)d_in[1];   // (L,P,V,Q)
    float* out = (float*)d_out;               // v (B,L,V) then T, D

    char* ws = (char*)d_ws;
    ushort* uhat = (ushort*)ws;                       // B*L*P*V bf16 = 128 MB
    size_t off = (size_t)B * L * P * V * 2;
    float* vbuf = (float*)(ws + off);  off += (size_t)B * L * V * 4;
    float* bbuf = (float*)(ws + off);  off += (size_t)B * P * L * 4;   // (B,P,L)
    float* cbuf = (float*)(ws + off);  off += (size_t)B * L * P * 4;   // (B,L,P)
    float* norms = (float*)(ws + off); off += (size_t)B * L * 4;
    float* Tsum = (float*)(ws + off);  off += 256;

    hipMemsetAsync(Tsum, 0, sizeof(float), stream);

    hipLaunchKernelGGL(k_uhat, dim3(16384), dim3(256), 0, stream, W, x, uhat);
    // iter 0: uniform c -> v0
    hipLaunchKernelGGL(k_s, dim3(L, B), dim3(256), 0, stream, uhat, (const float*)nullptr, vbuf, (float*)nullptr);
    // b1 = v0.u ; c1 = softmax_l(b1)
    hipLaunchKernelGGL(k_bc, dim3(P / 16, B), dim3(256), 0, stream, uhat, vbuf, bbuf, cbuf, Tsum, 0, 0);
    // iter 1: s(c1) -> v1
    hipLaunchKernelGGL(k_s, dim3(L, B), dim3(256), 0, stream, uhat, cbuf, vbuf, (float*)nullptr);
    // b2 = b1 + v1.u ; c2 = softmax_l(b2); T partials
    hipLaunchKernelGGL(k_bc, dim3(P / 16, B), dim3(256), 0, stream, uhat, vbuf, bbuf, cbuf, Tsum, 1, 1);
    // iter 2: s(c2) -> v2 -> d_out, norms
    hipLaunchKernelGGL(k_s, dim3(L, B), dim3(256), 0, stream, uhat, cbuf, out, norms);
    hipLaunchKernelGGL(k_final, dim3(1), dim3(64), 0, stream, Tsum, norms, out);
}

// Round 3
// 304.332 us; speedup vs baseline: 1.7609x; 1.1378x over previous
//
#include <hip/hip_runtime.h>
#include <hip/hip_bf16.h>

#define B 16
#define L 64
#define P 1024
#define V 64
#define Q 16
#define LN64 4.158883083359672f

static __device__ __forceinline__ float bf2f(ushort u) {
    return __uint_as_float(((unsigned int)u) << 16);
}
static __device__ __forceinline__ ushort f2bf(float f) {
    unsigned int x = __float_as_uint(f);
    unsigned int r = (x + 0x7fffu + ((x >> 16) & 1u)) >> 16;
    return (ushort)r;
}

static __device__ __forceinline__ float wsum64(float v) {
#pragma unroll
    for (int m = 32; m > 0; m >>= 1) v += __shfl_xor(v, m, 64);
    return v;
}
static __device__ __forceinline__ float wmax64(float v) {
#pragma unroll
    for (int m = 32; m > 0; m >>= 1) v = fmaxf(v, __shfl_xor(v, m, 64));
    return v;
}

// ---------------------------------------------------------------------------
// K_uhat v2: block = (p, l-half). 4 waves; wave w owns b in [4w,4w+4), lane = v.
// x[:,p,:] staged in LDS once -> 64 regs/thread, reused across 32 l's.
// Per l: 4 coalesced float4 W loads/lane (wave covers contiguous 4KB),
// 64 FMA, 4 coalesced 128B ushort stores. W loads double-buffered (2-deep).
// ---------------------------------------------------------------------------
__global__ __launch_bounds__(256) void k_uhat(const float* __restrict__ Wt,
                                              const float* __restrict__ x,
                                              ushort* __restrict__ uhat) {
    const int t = threadIdx.x;
    const int w = t >> 6;          // b-group
    const int lane = t & 63;       // v
    const int p = blockIdx.x >> 1;
    const int l0 = (blockIdx.x & 1) * 32;

    __shared__ float xs[B * Q];    // 1 KB
    {
        const int b = t >> 4, q = t & 15;
        xs[t] = x[((size_t)b * P + p) * Q + q];
    }
    __syncthreads();

    float xr[4][Q];                // wave's 4 b rows of x
#pragma unroll
    for (int i = 0; i < 4; ++i)
#pragma unroll
        for (int q = 0; q < Q; ++q) xr[i][q] = xs[(w * 4 + i) * Q + q];

    const float4* Wp0 = reinterpret_cast<const float4*>(Wt);

    float4 Wa[4], Wb[4];
#define LOADW(l, d)                                                          \
    {                                                                        \
        const float4* wp = Wp0 + (((size_t)(l) * P + p) * V + lane) * 4;     \
        d[0] = wp[0]; d[1] = wp[1]; d[2] = wp[2]; d[3] = wp[3];              \
    }
#define COMPUTE(l, Wr)                                                       \
    {                                                                        \
        _Pragma("unroll")                                                    \
        for (int i = 0; i < 4; ++i) {                                        \
            float u = 0.f;                                                   \
            _Pragma("unroll")                                                \
            for (int q4 = 0; q4 < 4; ++q4) {                                 \
                u = fmaf(Wr[q4].x, xr[i][q4 * 4 + 0], u);                    \
                u = fmaf(Wr[q4].y, xr[i][q4 * 4 + 1], u);                    \
                u = fmaf(Wr[q4].z, xr[i][q4 * 4 + 2], u);                    \
                u = fmaf(Wr[q4].w, xr[i][q4 * 4 + 3], u);                    \
            }                                                                \
            const int b = w * 4 + i;                                         \
            uhat[(((size_t)(b * L + (l))) * P + p) * V + lane] = f2bf(u);    \
        }                                                                    \
    }

    LOADW(l0, Wa);
#pragma unroll 2
    for (int li = 0; li < 32; li += 2) {
        LOADW(l0 + li + 1, Wb);
        COMPUTE(l0 + li, Wa);
        if (li + 2 < 32) LOADW(l0 + li + 2, Wa);
        COMPUTE(l0 + li + 1, Wb);
    }
#undef LOADW
#undef COMPUTE
}

// ---------------------------------------------------------------------------
// K_s: per (b,l) block. s[v] = sum_p c[p]*u[p,v], fused squash.
// Thread t owns (pl = t>>4, v0 = (t&15)*4); ushort4 loads; c staged in LDS.
// ---------------------------------------------------------------------------
__global__ __launch_bounds__(256) void k_s(const ushort* __restrict__ uhat,
                                           const float* __restrict__ c,
                                           float* __restrict__ vout,
                                           float* __restrict__ norms) {
    const int l = blockIdx.x, b = blockIdx.y;
    const int t = threadIdx.x;
    const int w = t >> 6, lane = t & 63;
    const int pl = t >> 4;      // 0..15
    const int vg = t & 15;      // v0 = vg*4

    __shared__ float csh[P];        // 4 KB
    __shared__ float4 sl[4][16];    // 1 KB

    const ushort* up = uhat + ((size_t)(b * L + l)) * P * V + (size_t)pl * V + vg * 4;

    float4 acc = {0.f, 0.f, 0.f, 0.f};
    if (c) {
        const float* cp = c + (size_t)(b * L + l) * P;
        reinterpret_cast<float4*>(csh)[t] = reinterpret_cast<const float4*>(cp)[t];
        __syncthreads();
#pragma unroll 8
        for (int i = 0; i < 64; ++i) {
            ushort4 u = *reinterpret_cast<const ushort4*>(up + (size_t)i * 16 * V);
            float cc = csh[pl + i * 16];
            acc.x = fmaf(cc, bf2f(u.x), acc.x);
            acc.y = fmaf(cc, bf2f(u.y), acc.y);
            acc.z = fmaf(cc, bf2f(u.z), acc.z);
            acc.w = fmaf(cc, bf2f(u.w), acc.w);
        }
    } else {
#pragma unroll 8
        for (int i = 0; i < 64; ++i) {
            ushort4 u = *reinterpret_cast<const ushort4*>(up + (size_t)i * 16 * V);
            acc.x += bf2f(u.x); acc.y += bf2f(u.y);
            acc.z += bf2f(u.z); acc.w += bf2f(u.w);
        }
        acc.x *= (1.f / 64.f); acc.y *= (1.f / 64.f);
        acc.z *= (1.f / 64.f); acc.w *= (1.f / 64.f);
    }
    // reduce the 4 pl-groups within the wave (lane bits 4,5)
#pragma unroll
    for (int m = 16; m <= 32; m <<= 1) {
        acc.x += __shfl_xor(acc.x, m, 64);
        acc.y += __shfl_xor(acc.y, m, 64);
        acc.z += __shfl_xor(acc.z, m, 64);
        acc.w += __shfl_xor(acc.w, m, 64);
    }
    if (lane < 16) sl[w][vg] = acc;
    __syncthreads();
    if (w == 0 && lane < 16) {
        float4 s0 = sl[0][vg], s1 = sl[1][vg], s2 = sl[2][vg], s3 = sl[3][vg];
        float4 s;
        s.x = s0.x + s1.x + s2.x + s3.x;
        s.y = s0.y + s1.y + s2.y + s3.y;
        s.z = s0.z + s1.z + s2.z + s3.z;
        s.w = s0.w + s1.w + s2.w + s3.w;
        float sq = s.x * s.x + s.y * s.y + s.z * s.z + s.w * s.w;
        sq += __shfl_xor(sq, 1, 64);
        sq += __shfl_xor(sq, 2, 64);
        sq += __shfl_xor(sq, 4, 64);
        sq += __shfl_xor(sq, 8, 64);
        float f = sqrtf(sq) / (1.0f + sq);
        float4 o = {s.x * f, s.y * f, s.z * f, s.w * f};
        *reinterpret_cast<float4*>(vout + (size_t)(b * L + l) * V + vg * 4) = o;
        if (norms && lane == 0) norms[b * L + l] = sq / (1.0f + sq);
    }
}

// ---------------------------------------------------------------------------
// K_bc: block = (b, 16 consecutive p). Phase 1: db[l,p] = sum_v v[l,v]*u[l,p,v]
// streamed coalesced over l (thread owns (pl, v0), 16-lane reduce).
// Phase 2: each wave softmaxes 4 p's over l; coalesced transpose-write of c.
// bbuf layout (B,P,L); cbuf layout (B,L,P).
// ---------------------------------------------------------------------------
__global__ __launch_bounds__(256) void k_bc(const ushort* __restrict__ uhat,
                                            const float* __restrict__ vv,
                                            float* __restrict__ bbuf,
                                            float* __restrict__ cbuf,
                                            float* __restrict__ Tsum,
                                            int add_prev, int do_T) {
    const int p0 = blockIdx.x * 16, b = blockIdx.y;
    const int t = threadIdx.x;
    const int w = t >> 6, lane = t & 63;
    const int pl = t >> 4;      // 0..15
    const int vg = t & 15;      // v0 = vg*4

    __shared__ float vsh[L][V];        // 16 KB
    __shared__ float bl[16][L + 1];    // db[p][l]
    __shared__ float ct[16][L + 1];    // c[p][l]

    // stage v[b,:,:] in LDS
    {
        const float4* vvp = reinterpret_cast<const float4*>(vv + (size_t)b * L * V);
        float4* vshp = reinterpret_cast<float4*>(&vsh[0][0]);
#pragma unroll
        for (int i = 0; i < 4; ++i) vshp[t + i * 256] = vvp[t + i * 256];
    }
    __syncthreads();

    // phase 1: stream u_hat, 16-lane reduce over v
    const ushort* up = uhat + (((size_t)b * L) * P + p0 + pl) * V + vg * 4;
#pragma unroll 8
    for (int l = 0; l < L; ++l) {
        ushort4 u = *reinterpret_cast<const ushort4*>(up + (size_t)l * P * V);
        float4 vf = *reinterpret_cast<const float4*>(&vsh[l][vg * 4]);
        float tacc = bf2f(u.x) * vf.x + bf2f(u.y) * vf.y +
                     bf2f(u.z) * vf.z + bf2f(u.w) * vf.w;
        tacc += __shfl_xor(tacc, 1, 64);
        tacc += __shfl_xor(tacc, 2, 64);
        tacc += __shfl_xor(tacc, 4, 64);
        tacc += __shfl_xor(tacc, 8, 64);
        if (vg == 0) bl[pl][l] = tacc;
    }
    __syncthreads();

    // phase 2: each wave softmaxes 4 p's (lane = l)
    float tloc = 0.f;
#pragma unroll
    for (int pi = 0; pi < 4; ++pi) {
        const int pli = w * 4 + pi;
        const int p = p0 + pli;
        float bv = bl[pli][lane];
        float* bp = bbuf + ((size_t)b * P + p) * L;
        if (add_prev) bv += bp[lane];
        bp[lane] = bv;
        float m = wmax64(bv);
        float e = __expf(bv - m);
        float ssum = wsum64(e);
        float cc = e / ssum;
        ct[pli][lane] = cc;
        if (do_T) tloc += cc * __logf(64.0f * (cc + 1e-12f));
    }
    if (do_T) {
        float dsum = wsum64(tloc);
        if (lane == 0) atomicAdd(Tsum, dsum * (1.0f / LN64));
    }
    __syncthreads();

    // coalesced transpose-write of c: thread t -> (l = t>>2, p = (t&3)*4 ..+3)
    {
        const int l = t >> 2, pq = (t & 3) * 4;
        float4 cw;
        cw.x = ct[pq + 0][l];
        cw.y = ct[pq + 1][l];
        cw.z = ct[pq + 2][l];
        cw.w = ct[pq + 3][l];
        *reinterpret_cast<float4*>(cbuf + ((size_t)b * L + l) * P + p0 + pq) = cw;
    }
}

// ---------------------------------------------------------------------------
// K_final: T and D. One block, 64 threads (lane = l).
// ---------------------------------------------------------------------------
__global__ void k_final(const float* __restrict__ Tsum,
                        const float* __restrict__ norms,
                        float* __restrict__ out) {
    const int lane = threadIdx.x & 63;
    float n[B];
    float sum = 0.f;
#pragma unroll
    for (int b = 0; b < B; ++b) { n[b] = norms[b * L + lane]; sum += n[b]; }
    const float mean = sum * (1.0f / B);
    float var = 0.f;
#pragma unroll
    for (int b = 0; b < B; ++b) { float d = n[b] - mean; var = fmaf(d, d, var); }
    var *= (1.0f / B);
    float sd = sqrtf(var);
    float D = wmax64(sd);
    if (lane == 0) {
        out[B * L * V] = Tsum[0] * (1.0f / (B * P));
        out[B * L * V + 1] = D;
    }
}

extern "C" void kernel_launch(void* const* d_in, const int* in_sizes, int n_in,
                              void* d_out, int out_size, void* d_ws, size_t ws_size,
                              hipStream_t stream) {
    const float* x = (const float*)d_in[0];   // (B,P,Q)
    const float* W = (const float*)d_in[1];   // (L,P,V,Q)
    float* out = (float*)d_out;               // v (B,L,V) then T, D

    char* ws = (char*)d_ws;
    ushort* uhat = (ushort*)ws;                       // B*L*P*V bf16 = 128 MB
    size_t off = (size_t)B * L * P * V * 2;
    float* vbuf = (float*)(ws + off);  off += (size_t)B * L * V * 4;
    float* bbuf = (float*)(ws + off);  off += (size_t)B * P * L * 4;   // (B,P,L)
    float* cbuf = (float*)(ws + off);  off += (size_t)B * L * P * 4;   // (B,L,P)
    float* norms = (float*)(ws + off); off += (size_t)B * L * 4;
    float* Tsum = (float*)(ws + off);  off += 256;

    hipMemsetAsync(Tsum, 0, sizeof(float), stream);

    hipLaunchKernelGGL(k_uhat, dim3(2048), dim3(256), 0, stream, W, x, uhat);
    // iter 0: uniform c -> v0
    hipLaunchKernelGGL(k_s, dim3(L, B), dim3(256), 0, stream, uhat, (const float*)nullptr, vbuf, (float*)nullptr);
    // b1 = v0.u ; c1 = softmax_l(b1)
    hipLaunchKernelGGL(k_bc, dim3(P / 16, B), dim3(256), 0, stream, uhat, vbuf, bbuf, cbuf, Tsum, 0, 0);
    // iter 1: s(c1) -> v1
    hipLaunchKernelGGL(k_s, dim3(L, B), dim3(256), 0, stream, uhat, cbuf, vbuf, (float*)nullptr);
    // b2 = b1 + v1.u ; c2 = softmax_l(b2); T partials
    hipLaunchKernelGGL(k_bc, dim3(P / 16, B), dim3(256), 0, stream, uhat, vbuf, bbuf, cbuf, Tsum, 1, 1);
    // iter 2: s(c2) -> v2 -> d_out, norms
    hipLaunchKernelGGL(k_s, dim3(L, B), dim3(256), 0, stream, uhat, cbuf, out, norms);
    hipLaunchKernelGGL(k_final, dim3(1), dim3(64), 0, stream, Tsum, norms, out);
}